// Round 5
// baseline (1238.845 us; speedup 1.0000x reference)
//
#include <hip/hip_runtime.h>

#define B_   128
#define T_   16

typedef __bf16 bf16;
typedef __bf16 bf16x8 __attribute__((ext_vector_type(8)));
typedef float f32x4 __attribute__((ext_vector_type(4)));

#define GLL(SRC, DST) __builtin_amdgcn_global_load_lds( \
    (const __attribute__((address_space(1))) void*)(SRC), \
    (__attribute__((address_space(3))) void*)(DST), 16, 0, 0)

__device__ __forceinline__ float sigf(float x) { return 1.f / (1.f + expf(-x)); }

// ---------------------------------------------------------------------------
// Split-K GEMM, partials only (used for the big encoder GEMM + base).
// Tile 128x128, BK=64, single-buffered LDS, 4 waves x 64x64.
// ---------------------------------------------------------------------------
__global__ __launch_bounds__(256) void gemm_k(
    const bf16* __restrict__ A, int lda,
    const bf16* __restrict__ W, int ldw, int Kc,
    float* __restrict__ part)
{
    __shared__ bf16 As[128 * 64];
    __shared__ bf16 Bs[128 * 64];

    const int nt = blockIdx.x, zz = blockIdx.y;
    const int tid = threadIdx.x, lane = tid & 63, wave = tid >> 6;
    const bf16* Ab = A + (size_t)zz * Kc;
    const bf16* Wb = W + (size_t)nt * 128 * ldw + (size_t)zz * Kc;

    const int srow = lane >> 3;
    const int scol = ((lane & 7) ^ srow) << 3;

    f32x4 acc[4][4];
#pragma unroll
    for (int m = 0; m < 4; ++m)
#pragma unroll
        for (int n = 0; n < 4; ++n) acc[m][n] = (f32x4){0.f, 0.f, 0.f, 0.f};

    const int wm = wave & 1, wn = wave >> 1;
    const int ln = lane & 15;
    const int rA = wm * 64 + ln;
    const int rB = wn * 64 + ln;
    const int swz = (lane & 7) << 4;
    const int kq  = (lane >> 4) << 4;

    const int nk = Kc >> 6;
    for (int it = 0; it < nk; ++it) {
        if (it) __syncthreads();
        const int koff = it << 6;
#pragma unroll
        for (int i = 0; i < 4; ++i) {
            int rb = i * 32 + wave * 8;
            GLL(Ab + (size_t)(rb + srow) * lda + koff + scol, &As[rb * 64]);
        }
#pragma unroll
        for (int i = 0; i < 4; ++i) {
            int rb = i * 32 + wave * 8;
            GLL(Wb + (size_t)(rb + srow) * ldw + koff + scol, &Bs[rb * 64]);
        }
        __syncthreads();
#pragma unroll
        for (int k2 = 0; k2 < 2; ++k2) {
            const int co = (((k2 << 6) | kq) ^ swz) >> 1;
            bf16x8 a[4], b[4];
#pragma unroll
            for (int f = 0; f < 4; ++f) a[f] = *(const bf16x8*)&As[(rA + f * 16) * 64 + co];
#pragma unroll
            for (int f = 0; f < 4; ++f) b[f] = *(const bf16x8*)&Bs[(rB + f * 16) * 64 + co];
#pragma unroll
            for (int m = 0; m < 4; ++m)
#pragma unroll
                for (int n = 0; n < 4; ++n)
                    acc[m][n] = __builtin_amdgcn_mfma_f32_16x16x32_bf16(a[m], b[n], acc[m][n], 0, 0, 0);
        }
    }

    float* myp = part + ((size_t)(zz * gridDim.x + nt)) * (128 * 128);
    const int q = lane >> 4;
#pragma unroll
    for (int m = 0; m < 4; ++m) {
        int row = wm * 64 + m * 16 + q * 4;
#pragma unroll
        for (int n = 0; n < 4; ++n) {
            int col = wn * 64 + n * 16 + ln;
#pragma unroll
            for (int r = 0; r < 4; ++r)
                myp[(size_t)(row + r) * 128 + col] = acc[m][n][r];
        }
    }
}

// ---------------------------------------------------------------------------
// fin: reduce ZN slices + epilogue (EP0 base, EP1 enc LSTM). grid (ntiles, 4).
// ---------------------------------------------------------------------------
template<int EP, int ZN>
__global__ __launch_bounds__(256) void fin_k(
    const float* __restrict__ part,
    const float* __restrict__ base,
    float* __restrict__ cst,
    bf16* __restrict__ aew,
    const float* __restrict__ b1, const float* __restrict__ b2)
{
    const int nt = blockIdx.x, rb = blockIdx.y;
    const int ntiles = gridDim.x;
    const size_t sl = (size_t)ntiles * (128 * 128);
    const float* p0 = part + (size_t)nt * (128 * 128);

#pragma unroll
    for (int it = 0; it < 4; ++it) {
        const int li  = it * 256 + threadIdx.x;
        const int row = rb * 32 + (li >> 5);
        const int cq  = li & 31;
        const int c0  = cq << 2;

        float s0 = 0.f, s1 = 0.f, s2 = 0.f, s3 = 0.f;
#pragma unroll
        for (int z = 0; z < ZN; ++z) {
            float4 p = *(const float4*)(p0 + (size_t)z * sl + (size_t)row * 128 + c0);
            s0 += p.x; s1 += p.y; s2 += p.z; s3 += p.w;
        }

        if (EP == 0) {
            int j = nt * 32 + cq;
            int nb = row * 4096 + nt * 128 + c0;
            cst[nb + 0] = s0 + b1[j]        + b2[j];
            cst[nb + 1] = s1 + b1[1024 + j] + b2[1024 + j];
            cst[nb + 2] = s2 + b1[2048 + j] + b2[2048 + j];
            cst[nb + 3] = s3 + b1[3072 + j] + b2[3072 + j];
        } else {
            int j = nt * 32 + cq;
            float4 bb = *(const float4*)(base + (size_t)row * 4096 + nt * 128 + c0);
            float gi = s0 + bb.x, gf = s1 + bb.y, gg = s2 + bb.z, go = s3 + bb.w;
            int ci = row * 1024 + j;
            float cn = sigf(gf) * cst[ci] + sigf(gi) * tanhf(gg);
            cst[ci] = cn;
            aew[(size_t)row * 6144 + 5120 + j] = (bf16)(sigf(go) * tanhf(cn));
        }
    }
}

// ---------------------------------------------------------------------------
// Fused no-split GEMM + epilogue for small-K GEMMs (ms/dec/wr).
// Tile 128(M) x 32(N), full K in-block, dbuf LDS, 4 waves each 32x32.
//  EP2: mu/sig interleaved -> z -> ad_out[0..256)
//  EP3: dec LSTM -> c_dec; h -> aew[4096+j], ad_out[256+j]
//  EP4: c_t += sum + b1; aew[n] = -sig(c); if(outp) outp = sig(c)
// ---------------------------------------------------------------------------
template<int EP>
__global__ __launch_bounds__(256) void gemmf(
    const bf16* __restrict__ A, int lda,
    const bf16* __restrict__ W, int ldw, int nk,   // K = nk*64
    float* __restrict__ cst,
    bf16* __restrict__ aew, bf16* __restrict__ ad_out,
    const float* __restrict__ b1, const float* __restrict__ b2,
    const float* __restrict__ eps_t, float* __restrict__ outp)
{
    __shared__ alignas(16) bf16 As[2][128 * 64];   // 2 x 16 KB (reused as Cl)
    __shared__ alignas(16) bf16 Ws[2][32 * 64];    // 2 x 4 KB

    const int nt = blockIdx.x;
    const int tid = threadIdx.x, lane = tid & 63, wave = tid >> 6;
    const bf16* Wb = W + (size_t)nt * 32 * ldw;

    const int srow = lane >> 3;
    const int scol = ((lane & 7) ^ srow) << 3;

    f32x4 acc[2][2];
#pragma unroll
    for (int m = 0; m < 2; ++m)
#pragma unroll
        for (int n = 0; n < 2; ++n) acc[m][n] = (f32x4){0.f, 0.f, 0.f, 0.f};

    auto stage = [&](int b, int koff) {
#pragma unroll
        for (int i = 0; i < 4; ++i) {
            int rb = i * 32 + wave * 8;
            GLL(A + (size_t)(rb + srow) * lda + koff + scol, &As[b][rb * 64]);
        }
        int rbw = wave * 8;
        GLL(Wb + (size_t)(rbw + srow) * ldw + koff + scol, &Ws[b][rbw * 64]);
    };

    const int ln = lane & 15;
    const int q  = lane >> 4;
    const int kq = q << 4;
    const int swz = (lane & 7) << 4;
    const int rA = wave * 32 + ln;

    stage(0, 0);
    int bq = 0;
    for (int it = 0; it < nk; ++it) {
        __syncthreads();
        if (it + 1 < nk) stage(bq ^ 1, (it + 1) << 6);
        const bf16* as = As[bq];
        const bf16* ws = Ws[bq];
#pragma unroll
        for (int k2 = 0; k2 < 2; ++k2) {
            const int co = (((k2 << 6) | kq) ^ swz) >> 1;
            bf16x8 a0 = *(const bf16x8*)&as[(rA)      * 64 + co];
            bf16x8 a1 = *(const bf16x8*)&as[(rA + 16) * 64 + co];
            bf16x8 b0 = *(const bf16x8*)&ws[(ln)      * 64 + co];
            bf16x8 b1v = *(const bf16x8*)&ws[(ln + 16) * 64 + co];
            acc[0][0] = __builtin_amdgcn_mfma_f32_16x16x32_bf16(a0, b0,  acc[0][0], 0, 0, 0);
            acc[0][1] = __builtin_amdgcn_mfma_f32_16x16x32_bf16(a0, b1v, acc[0][1], 0, 0, 0);
            acc[1][0] = __builtin_amdgcn_mfma_f32_16x16x32_bf16(a1, b0,  acc[1][0], 0, 0, 0);
            acc[1][1] = __builtin_amdgcn_mfma_f32_16x16x32_bf16(a1, b1v, acc[1][1], 0, 0, 0);
        }
        bq ^= 1;
    }

    // acc -> LDS (fp32 128 x 32, stride 33), then fused epilogue
    __syncthreads();
    float* Cl = (float*)&As[0][0];
#pragma unroll
    for (int m = 0; m < 2; ++m) {
        int row = wave * 32 + m * 16 + q * 4;
#pragma unroll
        for (int n = 0; n < 2; ++n) {
            int col = n * 16 + ln;
#pragma unroll
            for (int r = 0; r < 4; ++r)
                Cl[(row + r) * 33 + col] = acc[m][n][r];
        }
    }
    __syncthreads();

    if (EP == 2) {
        // 128 rows x 16 z-pairs; zi = nt*16 + zl
#pragma unroll
        for (int it = 0; it < 8; ++it) {
            int li = it * 256 + tid;
            int row = li >> 4, zl = li & 15;
            int zi = nt * 16 + zl;
            float mu = Cl[row * 33 + zl * 2]     + b1[zi];
            float ls = Cl[row * 33 + zl * 2 + 1] + b2[zi];
            float z = eps_t[row * 256 + zi] * expf(ls) + mu;
            ad_out[(size_t)row * 1280 + zi] = (bf16)z;
        }
    } else if (EP == 3) {
        // 128 rows x 8 quads; J = nt*8 + jl
#pragma unroll
        for (int it = 0; it < 4; ++it) {
            int li = it * 256 + tid;
            int row = li >> 3, jl = li & 7;
            int J = nt * 8 + jl;
            const float* cr = Cl + row * 33 + jl * 4;
            float gi = cr[0] + b1[J]        + b2[J];
            float gf = cr[1] + b1[1024 + J] + b2[1024 + J];
            float gg = cr[2] + b1[2048 + J] + b2[2048 + J];
            float go = cr[3] + b1[3072 + J] + b2[3072 + J];
            int ci = row * 1024 + J;
            float cn = sigf(gf) * cst[ci] + sigf(gi) * tanhf(gg);
            cst[ci] = cn;
            float h = sigf(go) * tanhf(cn);
            aew[(size_t)row * 6144 + 4096 + J] = (bf16)h;
            ad_out[(size_t)row * 1280 + 256 + J] = (bf16)h;
        }
    } else {  // EP == 4
        // 128 rows x 32 cols; n0 = nt*32 + c
#pragma unroll
        for (int it = 0; it < 16; ++it) {
            int li = it * 256 + tid;
            int row = li >> 5, c = li & 31;
            int n0 = nt * 32 + c;
            int ci = row * 4096 + n0;
            float cv = cst[ci] + Cl[row * 33 + c] + b1[n0];
            cst[ci] = cv;
            float sv = sigf(cv);
            aew[(size_t)row * 6144 + n0] = (bf16)(-sv);
            if (outp) outp[ci] = sv;
        }
    }
}

// ---------------- init + weight packing ----------------
#define PBL (B_ * 4096)
#define PBH (B_ * 1024)

__global__ void init_k(const float* __restrict__ x, const float* __restrict__ c0,
                       const float* __restrict__ h0e, const float* __restrict__ h0d,
                       float* __restrict__ c_t, float* __restrict__ c_enc,
                       float* __restrict__ c_dec, bf16* __restrict__ ae,
                       bf16* __restrict__ ad0, bf16* __restrict__ x_bf) {
    int i = blockIdx.x * 256 + threadIdx.x;
    if (i >= PBL) return;
    int b = i >> 12, n = i & 4095;
    float c = c0[n];
    c_t[i] = c;
    ae[(size_t)b * 6144 + n] = (bf16)(-sigf(c));
    x_bf[i] = (bf16)x[i];
    if (i < PBH) {
        int b2 = i >> 10, j = i & 1023;
        c_enc[i] = 0.f;
        c_dec[i] = 0.f;
        bf16 hd = (bf16)h0d[j], he = (bf16)h0e[j];
        ae[(size_t)b2 * 6144 + 4096 + j] = hd;
        ae[(size_t)b2 * 6144 + 5120 + j] = he;
        ad0[(size_t)b2 * 1280 + 256 + j] = hd;
    }
}

__device__ __forceinline__ bf16x8 cvt8(const float* s) {
    float4 a = *(const float4*)s, b = *(const float4*)(s + 4);
    bf16x8 v = { (bf16)a.x, (bf16)a.y, (bf16)a.z, (bf16)a.w,
                 (bf16)b.x, (bf16)b.y, (bf16)b.z, (bf16)b.w };
    return v;
}

// Merged: Wenc'[np][c] (xhat|hdec|hh) AND Wsum (x+xhat) — reads W_ih_e once.
__global__ void conv_es_k(const float* __restrict__ Wih, const float* __restrict__ Whh,
                          bf16* __restrict__ wenc, bf16* __restrict__ wsum) {
    int id = blockIdx.x * 256 + threadIdx.x;
    if (id >= 4096 * 768) return;
    int np = id / 768, c = (id - np * 768) * 8;
    int n = ((np & 3) << 10) + (np >> 2);
    if (c < 4096) {
        const float* sx = Wih + (size_t)n * 9216 + c;          // x part
        const float* sh = sx + 4096;                           // xhat part
        float4 a = *(const float4*)sh, b = *(const float4*)(sh + 4);
        float4 e = *(const float4*)sx, f = *(const float4*)(sx + 4);
        bf16x8 vh = { (bf16)a.x, (bf16)a.y, (bf16)a.z, (bf16)a.w,
                      (bf16)b.x, (bf16)b.y, (bf16)b.z, (bf16)b.w };
        bf16x8 vs = { (bf16)(a.x + e.x), (bf16)(a.y + e.y), (bf16)(a.z + e.z), (bf16)(a.w + e.w),
                      (bf16)(b.x + f.x), (bf16)(b.y + f.y), (bf16)(b.z + f.z), (bf16)(b.w + f.w) };
        *(bf16x8*)(wenc + (size_t)np * 6144 + c) = vh;
        *(bf16x8*)(wsum + (size_t)np * 4096 + c) = vs;
    } else {
        const float* src = (c < 5120) ? Wih + (size_t)n * 9216 + 8192 + (c - 4096)
                                      : Whh + (size_t)n * 1024 + (c - 5120);
        *(bf16x8*)(wenc + (size_t)np * 6144 + c) = cvt8(src);
    }
}

__global__ void conv_dec_k(const float* __restrict__ Wih, const float* __restrict__ Whh,
                           bf16* __restrict__ dst) {
    int id = blockIdx.x * 256 + threadIdx.x;
    if (id >= 4096 * 160) return;
    int np = id / 160, c = (id - np * 160) * 8;
    int n = ((np & 3) << 10) + (np >> 2);
    const float* src = (c < 256) ? Wih + (size_t)n * 256 + c
                                 : Whh + (size_t)n * 1024 + (c - 256);
    *(bf16x8*)(dst + (size_t)np * 1280 + c) = cvt8(src);
}

__global__ void conv_ms_k(const float* __restrict__ Wmu, const float* __restrict__ Wsig,
                          bf16* __restrict__ dst) {
    int id = blockIdx.x * 256 + threadIdx.x;
    if (id >= 512 * 128) return;
    int np = id >> 7, c = (id & 127) * 8;
    int zi = np >> 1;
    const float* src = ((np & 1) ? Wsig : Wmu) + (size_t)zi * 1024 + c;
    *(bf16x8*)(dst + (size_t)np * 1024 + c) = cvt8(src);
}

__global__ void conv_wr_k(const float* __restrict__ Wwr, bf16* __restrict__ dst) {
    int id = blockIdx.x * 256 + threadIdx.x;
    if (id >= 4096 * 128) return;
    *(bf16x8*)(dst + (size_t)id * 8) = cvt8(Wwr + (size_t)id * 8);
}

// ---------------- launch ----------------
extern "C" void kernel_launch(void* const* d_in, const int* in_sizes, int n_in,
                              void* d_out, int out_size, void* d_ws, size_t ws_size,
                              hipStream_t stream) {
    const float* x      = (const float*)d_in[0];
    const float* eps    = (const float*)d_in[1];
    const float* c0     = (const float*)d_in[2];
    const float* h0e    = (const float*)d_in[3];
    const float* h0d    = (const float*)d_in[4];
    const float* W_ih_e = (const float*)d_in[5];
    const float* b_ih_e = (const float*)d_in[6];
    const float* W_hh_e = (const float*)d_in[7];
    const float* b_hh_e = (const float*)d_in[8];
    const float* W_mu   = (const float*)d_in[9];
    const float* b_mu   = (const float*)d_in[10];
    const float* W_sig  = (const float*)d_in[11];
    const float* b_sig  = (const float*)d_in[12];
    const float* W_ih_d = (const float*)d_in[13];
    const float* b_ih_d = (const float*)d_in[14];
    const float* W_hh_d = (const float*)d_in[15];
    const float* b_hh_d = (const float*)d_in[16];
    const float* W_wr   = (const float*)d_in[17];
    const float* b_wr   = (const float*)d_in[18];
    float* out = (float*)d_out;

    float* f = (float*)d_ws;
    float* c_t   = f; f += 524288;
    float* base  = f; f += 524288;
    float* part  = f; f += (size_t)16 * 32 * 16384;   // 32 MB partials (enc z=16)
    float* c_enc = f; f += 131072;
    float* c_dec = f; f += 131072;
    bf16* bp      = (bf16*)f;
    bf16* act_enc = bp; bp += (size_t)B_ * 6144;
    bf16* ad0     = bp; bp += (size_t)B_ * 1280;      // act_dec ping
    bf16* ad1     = bp; bp += (size_t)B_ * 1280;      // act_dec pong
    bf16* x_bf    = bp; bp += (size_t)B_ * 4096;
    bf16* Wenc    = bp; bp += (size_t)4096 * 6144;
    bf16* Wsum    = bp; bp += (size_t)4096 * 4096;
    bf16* Wdec    = bp; bp += (size_t)4096 * 1280;
    bf16* Wms     = bp; bp += (size_t)512 * 1024;
    bf16* Wwr     = bp; bp += (size_t)4096 * 1024;

    dim3 blk(256);

    init_k<<<(PBL + 255) / 256, blk, 0, stream>>>(x, c0, h0e, h0d, c_t, c_enc, c_dec,
                                                  act_enc, ad0, x_bf);
    conv_es_k<<<(4096 * 768 + 255) / 256, blk, 0, stream>>>(W_ih_e, W_hh_e, Wenc, Wsum);
    conv_dec_k<<<(4096 * 160 + 255) / 256, blk, 0, stream>>>(W_ih_d, W_hh_d, Wdec);
    conv_ms_k<<<(512 * 128 + 255) / 256, blk, 0, stream>>>(W_mu, W_sig, Wms);
    conv_wr_k<<<(4096 * 128 + 255) / 256, blk, 0, stream>>>(W_wr, Wwr);

    // base = b_ih_e + b_hh_e + x @ Wsum^T  (gate-permuted), z=8
    gemm_k<<<dim3(32, 8), blk, 0, stream>>>(x_bf, 4096, Wsum, 4096, 512, part);
    fin_k<0, 8><<<dim3(32, 4), blk, 0, stream>>>(part, nullptr, base, nullptr,
                                                 b_ih_e, b_hh_e);

    for (int t = 0; t < T_; ++t) {
        bf16* ad_cur = (t & 1) ? ad1 : ad0;
        bf16* ad_nxt = (t & 1) ? ad0 : ad1;

        // encoder gates: [negs | h_dec | h_enc] @ Wenc^T, K=6144, split-K z=16
        gemm_k<<<dim3(32, 16), blk, 0, stream>>>(act_enc, 6144, Wenc, 6144, 384, part);
        fin_k<1, 16><<<dim3(32, 4), blk, 0, stream>>>(part, base, c_enc, act_enc,
                                                      nullptr, nullptr);
        // mu/sigma + reparam: h_enc @ Wms^T -> z into ad_cur[0..256)
        gemmf<2><<<dim3(16), blk, 0, stream>>>(act_enc + 5120, 6144, Wms, 1024, 16,
            nullptr, nullptr, ad_cur, b_mu, b_sig, eps + (size_t)t * (B_ * 256), nullptr);
        // decoder gates: [z | h_dec] @ Wdec^T, K=1280 -> h_dec_new into ad_nxt/aew
        gemmf<3><<<dim3(128), blk, 0, stream>>>(ad_cur, 1280, Wdec, 1280, 20,
            c_dec, act_enc, ad_nxt, b_ih_d, b_hh_d, nullptr, nullptr);
        // write: c_t += h_dec_new @ Wwr^T + b_wr; negs (+ out at last step)
        gemmf<4><<<dim3(128), blk, 0, stream>>>(ad_nxt + 256, 1280, Wwr, 1024, 16,
            c_t, act_enc, nullptr, b_wr, nullptr, nullptr,
            (t == T_ - 1) ? out : nullptr);
    }
}

// Round 6
// 1051.510 us; speedup vs baseline: 1.1782x; 1.1782x over previous
//
#include <hip/hip_runtime.h>

#define B_   128
#define T_   16

typedef __bf16 bf16;
typedef __bf16 bf16x8 __attribute__((ext_vector_type(8)));
typedef float f32x4 __attribute__((ext_vector_type(4)));

#define GLL(SRC, DST) __builtin_amdgcn_global_load_lds( \
    (const __attribute__((address_space(1))) void*)(SRC), \
    (__attribute__((address_space(3))) void*)(DST), 16, 0, 0)

#define MFMA __builtin_amdgcn_mfma_f32_16x16x32_bf16

__device__ __forceinline__ float sigf(float x) { return 1.f / (1.f + expf(-x)); }

// ---------------------------------------------------------------------------
// Split-K GEMM, partials only (encoder + base). Tile 128x128, BK=64,
// single-buffered LDS, 4 waves x 64x64. Proven in R4.
// ---------------------------------------------------------------------------
__global__ __launch_bounds__(256) void gemm_k(
    const bf16* __restrict__ A, int lda,
    const bf16* __restrict__ W, int ldw, int Kc,
    float* __restrict__ part)
{
    __shared__ bf16 As[128 * 64];
    __shared__ bf16 Bs[128 * 64];

    const int nt = blockIdx.x, zz = blockIdx.y;
    const int tid = threadIdx.x, lane = tid & 63, wave = tid >> 6;
    const bf16* Ab = A + (size_t)zz * Kc;
    const bf16* Wb = W + (size_t)nt * 128 * ldw + (size_t)zz * Kc;

    const int srow = lane >> 3;
    const int scol = ((lane & 7) ^ srow) << 3;

    f32x4 acc[4][4];
#pragma unroll
    for (int m = 0; m < 4; ++m)
#pragma unroll
        for (int n = 0; n < 4; ++n) acc[m][n] = (f32x4){0.f, 0.f, 0.f, 0.f};

    const int wm = wave & 1, wn = wave >> 1;
    const int ln = lane & 15;
    const int rA = wm * 64 + ln;
    const int rB = wn * 64 + ln;
    const int swz = (lane & 7) << 4;
    const int kq  = (lane >> 4) << 4;

    const int nk = Kc >> 6;
    for (int it = 0; it < nk; ++it) {
        if (it) __syncthreads();
        const int koff = it << 6;
#pragma unroll
        for (int i = 0; i < 4; ++i) {
            int rb = i * 32 + wave * 8;
            GLL(Ab + (size_t)(rb + srow) * lda + koff + scol, &As[rb * 64]);
        }
#pragma unroll
        for (int i = 0; i < 4; ++i) {
            int rb = i * 32 + wave * 8;
            GLL(Wb + (size_t)(rb + srow) * ldw + koff + scol, &Bs[rb * 64]);
        }
        __syncthreads();
#pragma unroll
        for (int k2 = 0; k2 < 2; ++k2) {
            const int co = (((k2 << 6) | kq) ^ swz) >> 1;
            bf16x8 a[4], b[4];
#pragma unroll
            for (int f = 0; f < 4; ++f) a[f] = *(const bf16x8*)&As[(rA + f * 16) * 64 + co];
#pragma unroll
            for (int f = 0; f < 4; ++f) b[f] = *(const bf16x8*)&Bs[(rB + f * 16) * 64 + co];
#pragma unroll
            for (int m = 0; m < 4; ++m)
#pragma unroll
                for (int n = 0; n < 4; ++n)
                    acc[m][n] = MFMA(a[m], b[n], acc[m][n], 0, 0, 0);
        }
    }

    float* myp = part + ((size_t)(zz * gridDim.x + nt)) * (128 * 128);
    const int q = lane >> 4;
#pragma unroll
    for (int m = 0; m < 4; ++m) {
        int row = wm * 64 + m * 16 + q * 4;
#pragma unroll
        for (int n = 0; n < 4; ++n) {
            int col = wn * 64 + n * 16 + ln;
#pragma unroll
            for (int r = 0; r < 4; ++r)
                myp[(size_t)(row + r) * 128 + col] = acc[m][n][r];
        }
    }
}

// ---------------------------------------------------------------------------
// Shared tile-128x32 GEMM core, BK=256 staged as 4x64-col chunks (short chain).
// ---------------------------------------------------------------------------
struct SmemG32 {
    bf16 As[4][128][64];   // 64 KB
    bf16 Ws[4][32][64];    // 16 KB
};

__device__ __forceinline__ void g32_core(SmemG32& sm, int nt,
    const bf16* __restrict__ A, int lda,
    const bf16* __restrict__ W, int ldw,
    int nk, f32x4 (&acc)[2][2])
{
    const int tid = threadIdx.x, lane = tid & 63, wave = tid >> 6;
    const int srow = lane >> 3;
    const int scol = ((lane & 7) ^ srow) << 3;
    const int ln = lane & 15;
    const int kq  = (lane >> 4) << 4;
    const int swz = (lane & 7) << 4;
    const int rA  = wave * 32 + ln;
    const bf16* Wb = W + (size_t)nt * 32 * ldw;

#pragma unroll
    for (int m = 0; m < 2; ++m)
#pragma unroll
        for (int n = 0; n < 2; ++n) acc[m][n] = (f32x4){0.f, 0.f, 0.f, 0.f};

    for (int it = 0; it < nk; ++it) {
        if (it) __syncthreads();
        const int koff = it * 256;
#pragma unroll
        for (int kc = 0; kc < 4; ++kc) {
            const int kg = koff + kc * 64 + scol;
#pragma unroll
            for (int i = 0; i < 4; ++i) {
                int rb = i * 32 + wave * 8;
                GLL(A + (size_t)(rb + srow) * lda + kg, &sm.As[kc][rb][0]);
            }
            GLL(Wb + (size_t)(wave * 8 + srow) * ldw + kg, &sm.Ws[kc][wave * 8][0]);
        }
        __syncthreads();
#pragma unroll
        for (int kc = 0; kc < 4; ++kc)
#pragma unroll
            for (int k2 = 0; k2 < 2; ++k2) {
                const int co = (((k2 << 6) | kq) ^ swz) >> 1;
                bf16x8 a0 = *(const bf16x8*)&sm.As[kc][rA][co];
                bf16x8 a1 = *(const bf16x8*)&sm.As[kc][rA + 16][co];
                bf16x8 b0 = *(const bf16x8*)&sm.Ws[kc][ln][co];
                bf16x8 b1 = *(const bf16x8*)&sm.Ws[kc][ln + 16][co];
                acc[0][0] = MFMA(a0, b0, acc[0][0], 0, 0, 0);
                acc[0][1] = MFMA(a0, b1, acc[0][1], 0, 0, 0);
                acc[1][0] = MFMA(a1, b0, acc[1][0], 0, 0, 0);
                acc[1][1] = MFMA(a1, b1, acc[1][1], 0, 0, 0);
            }
    }
    __syncthreads();
}

// ---------------------------------------------------------------------------
// kB: fin1 (enc reduce + LSTM -> h_enc) on blocks 0..383  ||
//     dec-hh GEMM (h_dec @ Whh_d^T, K=1024) -> gdhh fp32 on blocks 384..511
// ---------------------------------------------------------------------------
__global__ __launch_bounds__(256) void kB(
    const float* __restrict__ part, const float* __restrict__ base,
    float* __restrict__ c_enc, bf16* __restrict__ act,
    const bf16* __restrict__ hdec, const bf16* __restrict__ Wdec,
    float* __restrict__ gdhh)
{
    __shared__ SmemG32 sm;
    const int bid = blockIdx.x;
    if (bid >= 384) {
        const int nt2 = bid - 384;               // 0..127, cols np = nt2*32..+32
        f32x4 acc[2][2];
        g32_core(sm, nt2, hdec, 1024, Wdec + 256, 1280, 4, acc);
        const int tid = threadIdx.x, lane = tid & 63, wave = tid >> 6;
        const int ln = lane & 15, q = lane >> 4;
#pragma unroll
        for (int f = 0; f < 2; ++f)
#pragma unroll
            for (int n = 0; n < 2; ++n)
#pragma unroll
                for (int r = 0; r < 4; ++r)
                    gdhh[(size_t)(wave * 32 + f * 16 + q * 4 + r) * 4096
                         + nt2 * 32 + n * 16 + ln] = acc[f][n][r];
    } else {
        for (int i = bid * 256 + threadIdx.x; i < 131072; i += 98304) {
            const int row = i >> 10, j = i & 1023;
            const int nt = j >> 5, lc = (j & 31) << 2;
            const float* p0 = part + (size_t)nt * 16384 + (size_t)row * 128 + lc;
            float s0 = 0.f, s1 = 0.f, s2 = 0.f, s3 = 0.f;
#pragma unroll
            for (int z = 0; z < 16; ++z) {
                float4 p = *(const float4*)(p0 + (size_t)z * 524288);
                s0 += p.x; s1 += p.y; s2 += p.z; s3 += p.w;
            }
            float4 bb = *(const float4*)(base + (size_t)row * 4096 + (j << 2));
            float gi = s0 + bb.x, gf = s1 + bb.y, gg = s2 + bb.z, go = s3 + bb.w;
            float cn = sigf(gf) * c_enc[i] + sigf(gi) * tanhf(gg);
            c_enc[i] = cn;
            act[(size_t)row * 6144 + 5120 + j] = (bf16)(sigf(go) * tanhf(cn));
        }
    }
}

// ---------------------------------------------------------------------------
// g32_k<EP>: tile 128x32 GEMM + fused epilogue.
//  EP1 (ms): mu/sig interleaved cols -> z -> zbf       (grid 16, nk 4)
//  EP2 (wr): c_t += . + b_wr; negs -> act; opt out     (grid 128, nk 4)
// ---------------------------------------------------------------------------
template<int EP>
__global__ __launch_bounds__(256) void g32_k(
    const bf16* __restrict__ A, int lda,
    const bf16* __restrict__ W, int ldw, int nk,
    float* __restrict__ cst, bf16* __restrict__ o1,
    const float* __restrict__ b1, const float* __restrict__ b2,
    const float* __restrict__ eps_t, float* __restrict__ outp)
{
    __shared__ SmemG32 sm;
    const int nt = blockIdx.x;
    f32x4 acc[2][2];
    g32_core(sm, nt, A, lda, W, ldw, nk, acc);

    float* Cl = (float*)&sm;
    const int tid = threadIdx.x, lane = tid & 63, wave = tid >> 6;
    const int ln = lane & 15, q = lane >> 4;
#pragma unroll
    for (int f = 0; f < 2; ++f)
#pragma unroll
        for (int n = 0; n < 2; ++n)
#pragma unroll
            for (int r = 0; r < 4; ++r)
                Cl[(wave * 32 + f * 16 + q * 4 + r) * 33 + n * 16 + ln] = acc[f][n][r];
    __syncthreads();

    if (EP == 1) {
#pragma unroll
        for (int it = 0; it < 8; ++it) {
            int li = it * 256 + tid;
            int row = li >> 4, zl = li & 15;
            int zi = nt * 16 + zl;
            float mu = Cl[row * 33 + zl * 2]     + b1[zi];
            float ls = Cl[row * 33 + zl * 2 + 1] + b2[zi];
            float z = eps_t[row * 256 + zi] * expf(ls) + mu;
            o1[(size_t)row * 256 + zi] = (bf16)z;
        }
    } else {
#pragma unroll
        for (int it = 0; it < 16; ++it) {
            int li = it * 256 + tid;
            int row = li >> 5, c = li & 31;
            int n0 = nt * 32 + c;
            int ci = row * 4096 + n0;
            float cv = cst[ci] + Cl[row * 33 + c] + b1[n0];
            cst[ci] = cv;
            float sv = sigf(cv);
            o1[(size_t)row * 6144 + n0] = (bf16)(-sv);
            if (outp) outp[ci] = sv;
        }
    }
}

// ---------------------------------------------------------------------------
// kD: dec z-part (K=256, one-shot) + gdhh + biases + LSTM -> h_dec.
// Tile 128x64, grid 64.
// ---------------------------------------------------------------------------
struct SmemD {
    bf16 As[4][128][64];   // 64 KB
    bf16 Ws[4][64][64];    // 32 KB
};

__global__ __launch_bounds__(256) void kD(
    const bf16* __restrict__ zbf, const bf16* __restrict__ Wdec,
    const float* __restrict__ gdhh,
    const float* __restrict__ b_ihd, const float* __restrict__ b_hhd,
    float* __restrict__ c_dec, bf16* __restrict__ act, bf16* __restrict__ hdec)
{
    __shared__ SmemD sm;
    const int nt = blockIdx.x;                 // cols np = nt*64..+64
    const int tid = threadIdx.x, lane = tid & 63, wave = tid >> 6;
    const int srow = lane >> 3, scol = ((lane & 7) ^ srow) << 3;
    const int ln = lane & 15, q = lane >> 4;
    const int kq = q << 4, swz = (lane & 7) << 4;
    const int wr = wave & 1, wc = wave >> 1;
    const bf16* Wb = Wdec + (size_t)nt * 64 * 1280;

    f32x4 acc[4][2];
#pragma unroll
    for (int f = 0; f < 4; ++f)
#pragma unroll
        for (int n = 0; n < 2; ++n) acc[f][n] = (f32x4){0.f, 0.f, 0.f, 0.f};

#pragma unroll
    for (int kc = 0; kc < 4; ++kc) {
        const int kg = kc * 64 + scol;
#pragma unroll
        for (int i = 0; i < 4; ++i) {
            int rb = i * 32 + wave * 8;
            GLL(zbf + (size_t)(rb + srow) * 256 + kg, &sm.As[kc][rb][0]);
        }
#pragma unroll
        for (int i = 0; i < 2; ++i) {
            int rbw = i * 32 + wave * 8;
            GLL(Wb + (size_t)(rbw + srow) * 1280 + kg, &sm.Ws[kc][rbw][0]);
        }
    }
    __syncthreads();
#pragma unroll
    for (int kc = 0; kc < 4; ++kc)
#pragma unroll
        for (int k2 = 0; k2 < 2; ++k2) {
            const int co = (((k2 << 6) | kq) ^ swz) >> 1;
            bf16x8 b0 = *(const bf16x8*)&sm.Ws[kc][wc * 32 + ln][co];
            bf16x8 b1 = *(const bf16x8*)&sm.Ws[kc][wc * 32 + ln + 16][co];
#pragma unroll
            for (int f = 0; f < 4; ++f) {
                bf16x8 a = *(const bf16x8*)&sm.As[kc][wr * 64 + f * 16 + ln][co];
                acc[f][0] = MFMA(a, b0, acc[f][0], 0, 0, 0);
                acc[f][1] = MFMA(a, b1, acc[f][1], 0, 0, 0);
            }
        }
    __syncthreads();

    float* Cl = (float*)&sm;
#pragma unroll
    for (int f = 0; f < 4; ++f)
#pragma unroll
        for (int n = 0; n < 2; ++n)
#pragma unroll
            for (int r = 0; r < 4; ++r)
                Cl[(wr * 64 + f * 16 + q * 4 + r) * 66 + wc * 32 + n * 16 + ln] = acc[f][n][r];
    __syncthreads();

#pragma unroll
    for (int it = 0; it < 8; ++it) {
        int li = it * 256 + tid;
        int row = li >> 4, jl = li & 15;
        int J = nt * 16 + jl;
        const float* cr = &Cl[row * 66 + jl * 4];
        const float* gr = &gdhh[(size_t)row * 4096 + nt * 64 + jl * 4];
        float gi = cr[0] + gr[0] + b_ihd[J]        + b_hhd[J];
        float gf = cr[1] + gr[1] + b_ihd[1024 + J] + b_hhd[1024 + J];
        float gg = cr[2] + gr[2] + b_ihd[2048 + J] + b_hhd[2048 + J];
        float go = cr[3] + gr[3] + b_ihd[3072 + J] + b_hhd[3072 + J];
        int ci = row * 1024 + J;
        float cn = sigf(gf) * c_dec[ci] + sigf(gi) * tanhf(gg);
        c_dec[ci] = cn;
        float h = sigf(go) * tanhf(cn);
        act[(size_t)row * 6144 + 4096 + J] = (bf16)h;
        hdec[ci] = (bf16)h;
    }
}

// ---------------------------------------------------------------------------
// fin0: reduce 8 slices -> base (+ biases), gate-permuted cols. grid (32,4).
// ---------------------------------------------------------------------------
__global__ __launch_bounds__(256) void fin0_k(
    const float* __restrict__ part, float* __restrict__ base,
    const float* __restrict__ b1, const float* __restrict__ b2)
{
    const int nt = blockIdx.x, rb = blockIdx.y;
    const float* p0 = part + (size_t)nt * 16384;
#pragma unroll
    for (int it = 0; it < 4; ++it) {
        const int li = it * 256 + threadIdx.x;
        const int row = rb * 32 + (li >> 5);
        const int cq = li & 31;
        const int c0 = cq << 2;
        float s0 = 0.f, s1 = 0.f, s2 = 0.f, s3 = 0.f;
#pragma unroll
        for (int z = 0; z < 8; ++z) {
            float4 p = *(const float4*)(p0 + (size_t)z * 524288 + (size_t)row * 128 + c0);
            s0 += p.x; s1 += p.y; s2 += p.z; s3 += p.w;
        }
        int j = nt * 32 + cq;
        int nb = row * 4096 + nt * 128 + c0;
        base[nb + 0] = s0 + b1[j]        + b2[j];
        base[nb + 1] = s1 + b1[1024 + j] + b2[1024 + j];
        base[nb + 2] = s2 + b1[2048 + j] + b2[2048 + j];
        base[nb + 3] = s3 + b1[3072 + j] + b2[3072 + j];
    }
}

// ---------------- init + weight packing ----------------
#define PBL (B_ * 4096)
#define PBH (B_ * 1024)

__global__ void init_k(const float* __restrict__ x, const float* __restrict__ c0,
                       const float* __restrict__ h0e, const float* __restrict__ h0d,
                       float* __restrict__ c_t, float* __restrict__ c_enc,
                       float* __restrict__ c_dec, bf16* __restrict__ ae,
                       bf16* __restrict__ hdec, bf16* __restrict__ x_bf) {
    int i = blockIdx.x * 256 + threadIdx.x;
    if (i >= PBL) return;
    int b = i >> 12, n = i & 4095;
    float c = c0[n];
    c_t[i] = c;
    ae[(size_t)b * 6144 + n] = (bf16)(-sigf(c));
    x_bf[i] = (bf16)x[i];
    if (i < PBH) {
        int b2 = i >> 10, j = i & 1023;
        c_enc[i] = 0.f;
        c_dec[i] = 0.f;
        bf16 hd = (bf16)h0d[j], he = (bf16)h0e[j];
        ae[(size_t)b2 * 6144 + 4096 + j] = hd;
        ae[(size_t)b2 * 6144 + 5120 + j] = he;
        hdec[i] = hd;
    }
}

__device__ __forceinline__ bf16x8 cvt8(const float* s) {
    float4 a = *(const float4*)s, b = *(const float4*)(s + 4);
    bf16x8 v = { (bf16)a.x, (bf16)a.y, (bf16)a.z, (bf16)a.w,
                 (bf16)b.x, (bf16)b.y, (bf16)b.z, (bf16)b.w };
    return v;
}

// Wenc'[np][6144] (xhat|hdec|henc) AND Wsum (x+xhat); np = 4j+g <-> n = g*1024+j
__global__ void conv_es_k(const float* __restrict__ Wih, const float* __restrict__ Whh,
                          bf16* __restrict__ wenc, bf16* __restrict__ wsum) {
    int id = blockIdx.x * 256 + threadIdx.x;
    if (id >= 4096 * 768) return;
    int np = id / 768, c = (id - np * 768) * 8;
    int n = ((np & 3) << 10) + (np >> 2);
    if (c < 4096) {
        const float* sx = Wih + (size_t)n * 9216 + c;
        const float* sh = sx + 4096;
        float4 a = *(const float4*)sh, b = *(const float4*)(sh + 4);
        float4 e = *(const float4*)sx, f = *(const float4*)(sx + 4);
        bf16x8 vh = { (bf16)a.x, (bf16)a.y, (bf16)a.z, (bf16)a.w,
                      (bf16)b.x, (bf16)b.y, (bf16)b.z, (bf16)b.w };
        bf16x8 vs = { (bf16)(a.x + e.x), (bf16)(a.y + e.y), (bf16)(a.z + e.z), (bf16)(a.w + e.w),
                      (bf16)(b.x + f.x), (bf16)(b.y + f.y), (bf16)(b.z + f.z), (bf16)(b.w + f.w) };
        *(bf16x8*)(wenc + (size_t)np * 6144 + c) = vh;
        *(bf16x8*)(wsum + (size_t)np * 4096 + c) = vs;
    } else {
        const float* src = (c < 5120) ? Wih + (size_t)n * 9216 + 8192 + (c - 4096)
                                      : Whh + (size_t)n * 1024 + (c - 5120);
        *(bf16x8*)(wenc + (size_t)np * 6144 + c) = cvt8(src);
    }
}

__global__ void conv_dec_k(const float* __restrict__ Wih, const float* __restrict__ Whh,
                           bf16* __restrict__ dst) {
    int id = blockIdx.x * 256 + threadIdx.x;
    if (id >= 4096 * 160) return;
    int np = id / 160, c = (id - np * 160) * 8;
    int n = ((np & 3) << 10) + (np >> 2);
    const float* src = (c < 256) ? Wih + (size_t)n * 256 + c
                                 : Whh + (size_t)n * 1024 + (c - 256);
    *(bf16x8*)(dst + (size_t)np * 1280 + c) = cvt8(src);
}

// Wms'[np][k]: np = 2*zi + s; s=0 -> Wmu[zi], s=1 -> Wsig[zi]
__global__ void conv_ms_k(const float* __restrict__ Wmu, const float* __restrict__ Wsig,
                          bf16* __restrict__ dst) {
    int id = blockIdx.x * 256 + threadIdx.x;
    if (id >= 512 * 128) return;
    int np = id >> 7, c = (id & 127) * 8;
    int zi = np >> 1;
    const float* src = ((np & 1) ? Wsig : Wmu) + (size_t)zi * 1024 + c;
    *(bf16x8*)(dst + (size_t)np * 1024 + c) = cvt8(src);
}

__global__ void conv_wr_k(const float* __restrict__ Wwr, bf16* __restrict__ dst) {
    int id = blockIdx.x * 256 + threadIdx.x;
    if (id >= 4096 * 128) return;
    *(bf16x8*)(dst + (size_t)id * 8) = cvt8(Wwr + (size_t)id * 8);
}

// ---------------- launch ----------------
extern "C" void kernel_launch(void* const* d_in, const int* in_sizes, int n_in,
                              void* d_out, int out_size, void* d_ws, size_t ws_size,
                              hipStream_t stream) {
    const float* x      = (const float*)d_in[0];
    const float* eps    = (const float*)d_in[1];
    const float* c0     = (const float*)d_in[2];
    const float* h0e    = (const float*)d_in[3];
    const float* h0d    = (const float*)d_in[4];
    const float* W_ih_e = (const float*)d_in[5];
    const float* b_ih_e = (const float*)d_in[6];
    const float* W_hh_e = (const float*)d_in[7];
    const float* b_hh_e = (const float*)d_in[8];
    const float* W_mu   = (const float*)d_in[9];
    const float* b_mu   = (const float*)d_in[10];
    const float* W_sig  = (const float*)d_in[11];
    const float* b_sig  = (const float*)d_in[12];
    const float* W_ih_d = (const float*)d_in[13];
    const float* b_ih_d = (const float*)d_in[14];
    const float* W_hh_d = (const float*)d_in[15];
    const float* b_hh_d = (const float*)d_in[16];
    const float* W_wr   = (const float*)d_in[17];
    const float* b_wr   = (const float*)d_in[18];
    float* out = (float*)d_out;

    float* f = (float*)d_ws;
    float* c_t   = f; f += 524288;
    float* base  = f; f += 524288;
    float* part  = f; f += (size_t)16 * 32 * 16384;   // 32 MB (enc z=16)
    float* c_enc = f; f += 131072;
    float* c_dec = f; f += 131072;
    float* gdhh  = f; f += 524288;
    bf16* bp      = (bf16*)f;
    bf16* act     = bp; bp += (size_t)B_ * 6144;
    bf16* hdec    = bp; bp += (size_t)B_ * 1024;
    bf16* zbf     = bp; bp += (size_t)B_ * 256;
    bf16* x_bf    = bp; bp += (size_t)B_ * 4096;
    bf16* Wenc    = bp; bp += (size_t)4096 * 6144;
    bf16* Wsum    = bp; bp += (size_t)4096 * 4096;
    bf16* Wdec    = bp; bp += (size_t)4096 * 1280;
    bf16* Wms     = bp; bp += (size_t)512 * 1024;
    bf16* Wwr     = bp; bp += (size_t)4096 * 1024;

    dim3 blk(256);

    init_k<<<(PBL + 255) / 256, blk, 0, stream>>>(x, c0, h0e, h0d, c_t, c_enc, c_dec,
                                                  act, hdec, x_bf);
    conv_es_k<<<(4096 * 768 + 255) / 256, blk, 0, stream>>>(W_ih_e, W_hh_e, Wenc, Wsum);
    conv_dec_k<<<(4096 * 160 + 255) / 256, blk, 0, stream>>>(W_ih_d, W_hh_d, Wdec);
    conv_ms_k<<<(512 * 128 + 255) / 256, blk, 0, stream>>>(W_mu, W_sig, Wms);
    conv_wr_k<<<(4096 * 128 + 255) / 256, blk, 0, stream>>>(W_wr, Wwr);

    // base = b_ih_e + b_hh_e + x @ Wsum^T  (gate-permuted), z=8
    gemm_k<<<dim3(32, 8), blk, 0, stream>>>(x_bf, 4096, Wsum, 4096, 512, part);
    fin0_k<<<dim3(32, 4), blk, 0, stream>>>(part, base, b_ih_e, b_hh_e);

    for (int t = 0; t < T_; ++t) {
        // A: encoder gates [negs | h_dec | h_enc] @ Wenc^T, split-K z=16
        gemm_k<<<dim3(32, 16), blk, 0, stream>>>(act, 6144, Wenc, 6144, 384, part);
        // B: fin1 (h_enc) || dec-hh GEMM (gdhh)
        kB<<<dim3(512), blk, 0, stream>>>(part, base, c_enc, act, hdec, Wdec, gdhh);
        // C: mu/sigma + reparam -> zbf
        g32_k<1><<<dim3(16), blk, 0, stream>>>(act + 5120, 6144, Wms, 1024, 4,
            nullptr, zbf, b_mu, b_sig, eps + (size_t)t * (B_ * 256), nullptr);
        // D: dec z-part + gdhh + LSTM -> h_dec
        kD<<<dim3(64), blk, 0, stream>>>(zbf, Wdec, gdhh, b_ih_d, b_hh_d,
                                         c_dec, act, hdec);
        // E: write head + c_t + negs (+ out)
        g32_k<2><<<dim3(128), blk, 0, stream>>>(hdec, 1024, Wwr, 1024, 4,
            c_t, act, b_wr, nullptr, nullptr, (t == T_ - 1) ? out : nullptr);
    }
}